// Round 6
// baseline (594.280 us; speedup 1.0000x reference)
//
#include <hip/hip_runtime.h>
#include <hip/hip_bf16.h>

typedef __hip_bfloat16 bf16;
typedef __attribute__((ext_vector_type(8))) short short8;
typedef __attribute__((ext_vector_type(4))) short short4v;
typedef __attribute__((ext_vector_type(4))) float f32x4;

#define MFMA_BF16(a, b, c) __builtin_amdgcn_mfma_f32_16x16x32_bf16((a), (b), (c), 0, 0, 0)

// 1/sqrt(E/H) * log2(e) folded into Wqkv q-rows: softmax exps become plain exp2
#define QSCALE 0.1803368860111270f

__device__ __forceinline__ short f2bf(float f) {
    union { bf16 h; short s; } u;
    u.h = __float2bfloat16(f);
    return u.s;
}

#if defined(__has_builtin) && __has_builtin(__builtin_amdgcn_cvt_pk_bf16_f32)
typedef __attribute__((ext_vector_type(2))) __bf16 bf16x2_t;
__device__ __forceinline__ unsigned int pk2(float a, float b) {
    union { bf16x2_t v; unsigned int u; } x;
    x.v = __builtin_amdgcn_cvt_pk_bf16_f32(a, b);
    return x.u;
}
#else
__device__ __forceinline__ unsigned int pk2(float a, float b) {
    union { bf16 h[2]; unsigned int u; } x;
    x.h[0] = __float2bfloat16(a);
    x.h[1] = __float2bfloat16(b);
    return x.u;
}
#endif

// ---------------- ALL converts in one dispatch (grid.y selects tensor / mode) ----------------
// y=0..3: plain convert (x, y, Wout1, Wout2). y=4,5: Wqkv row-permute + q-scale.
// NOTE (R5 lesson): do NOT fold the x/y convert into GEMM staging — the cvt VALU chain on
// the prefetched values forces vmcnt(0) before the MFMA block and exposes full HBM latency.
__global__ void cvt_fused(const float* __restrict__ x, const float* __restrict__ y,
                          const float* __restrict__ wo1, const float* __restrict__ wo2,
                          const float* __restrict__ wq1, const float* __restrict__ wq2,
                          bf16* __restrict__ ox, bf16* __restrict__ oy,
                          bf16* __restrict__ oo1, bf16* __restrict__ oo2,
                          bf16* __restrict__ oq1, bf16* __restrict__ oq2) {
    const int yb = blockIdx.y;
    if (yb < 4) {
        int i = blockIdx.x * 256 + threadIdx.x;
        const float* src; bf16* dst; int n4;
        switch (yb) {
            case 0:  src = x;   dst = ox;  n4 = 1048576; break;
            case 1:  src = y;   dst = oy;  n4 = 1048576; break;
            case 2:  src = wo1; dst = oo1; n4 = 262144;  break;
            default: src = wo2; dst = oo2; n4 = 262144;  break;
        }
        if (i >= n4) return;
        float4 f = reinterpret_cast<const float4*>(src)[i];
        short4v s;
        s.x = f2bf(f.x); s.y = f2bf(f.y); s.z = f2bf(f.z); s.w = f2bf(f.w);
        reinterpret_cast<short4v*>(dst)[i] = s;
    } else {
        // dest row n' = comp*1024 + h*64 + d  <-  src row d*48 + comp*16 + h
        const int np = blockIdx.x;
        if (np >= 3072) return;
        const int comp = np >> 10, rem = np & 1023, h = rem >> 6, d = rem & 63;
        const int srow = d * 48 + comp * 16 + h;
        const float* src = ((yb == 5) ? wq2 : wq1) + (long)srow * 1024;
        bf16* dst = ((yb == 5) ? oq2 : oq1) + (long)np * 1024;
        const float sc = (comp == 0) ? QSCALE : 1.0f;
        int t = threadIdx.x;
        float4 f = reinterpret_cast<const float4*>(src)[t];
        short4v s;
        s.x = f2bf(f.x * sc); s.y = f2bf(f.y * sc); s.z = f2bf(f.z * sc); s.w = f2bf(f.w * sc);
        reinterpret_cast<short4v*>(dst)[t] = s;
    }
}

// ---------------- GEMM, reg-prefetch + LDS dbuf K-loop, conflict-free 36-short rows ----------------
// 128x128 tile, BK=32, K=1024, bf16 A and B. LDS row stride 36 shorts (18 dwords, ==2 mod 4:
// every quarter-wave b128 phase lands on 16 distinct even banks -> 2-way = free;
// verified R5: conflicts 12.8M -> 0.39M).
// MODE 0 (qkv): N=3072; x<8 -> q packed [bh][t][d]; 8..15 -> k packed; 16..23 -> vT [bh][d][t].
// MODE 1 (out-proj): N=1024; fp32 C.
template <int MODE>
__global__ __launch_bounds__(256)
void gemm_k(const bf16* __restrict__ A0g, const bf16* __restrict__ B0g,
            void* o0a, void* o0b, void* o0c,
            const bf16* __restrict__ A1g, const bf16* __restrict__ B1g,
            void* o1a, void* o1b, void* o1c, int N) {
    __shared__ short smem[18432];   // 2 bufs x (A 4608 + B 4608) shorts
    const int z = blockIdx.z;
    const int tid  = threadIdx.x;
    const int lane = tid & 63;
    const int w    = tid >> 6;
    const int wr   = w >> 1;
    const int wc   = w & 1;
    const int quad = lane >> 4;
    const int l16  = lane & 15;
    const long bM = (long)blockIdx.y * 128;

    f32x4 acc[4][4] = {};

    const int srow = tid >> 2;          // 0..63
    const int sch  = (tid & 3) * 8;     // k-chunk of 8 bf16
    const short* Ag0 = reinterpret_cast<const short*>(z ? A1g : A0g) + (bM + srow) * 1024 + sch;
    const short* Bg0 = reinterpret_cast<const short*>(z ? B1g : B0g)
                       + ((long)blockIdx.x * 128 + srow) * 1024 + sch;
    const int sbase = srow * 36 + sch;

    // prologue: tile 0 -> buf 0
    {
        short8 a0 = *reinterpret_cast<const short8*>(Ag0);
        short8 a1 = *reinterpret_cast<const short8*>(Ag0 + 65536);
        short8 b0 = *reinterpret_cast<const short8*>(Bg0);
        short8 b1 = *reinterpret_cast<const short8*>(Bg0 + 65536);
        *reinterpret_cast<short8*>(&smem[sbase]) = a0;
        *reinterpret_cast<short8*>(&smem[sbase + 2304]) = a1;
        *reinterpret_cast<short8*>(&smem[sbase + 4608]) = b0;
        *reinterpret_cast<short8*>(&smem[sbase + 4608 + 2304]) = b1;
    }
    __syncthreads();

    for (int iter = 0; iter < 32; ++iter) {
        const int cur = iter & 1;
        short8 pa0, pa1, pb0, pb1;
        if (iter < 31) {
            const int off = (iter + 1) * 32;
            pa0 = *reinterpret_cast<const short8*>(Ag0 + off);
            pa1 = *reinterpret_cast<const short8*>(Ag0 + 65536 + off);
            pb0 = *reinterpret_cast<const short8*>(Bg0 + off);
            pb1 = *reinterpret_cast<const short8*>(Bg0 + 65536 + off);
        }
        const short* Ab = smem + cur * 9216;
        const short* Bb = Ab + 4608;

        short8 af[4], bfr[4];
#pragma unroll
        for (int mt = 0; mt < 4; ++mt)
            af[mt] = *reinterpret_cast<const short8*>(&Ab[(wr * 64 + mt * 16 + l16) * 36 + quad * 8]);
#pragma unroll
        for (int nt = 0; nt < 4; ++nt)
            bfr[nt] = *reinterpret_cast<const short8*>(&Bb[(wc * 64 + nt * 16 + l16) * 36 + quad * 8]);
#pragma unroll
        for (int mt = 0; mt < 4; ++mt)
#pragma unroll
            for (int nt = 0; nt < 4; ++nt)
                acc[mt][nt] = MFMA_BF16(af[mt], bfr[nt], acc[mt][nt]);

        if (iter < 31) {
            short* Sn = smem + (cur ^ 1) * 9216 + sbase;
            *reinterpret_cast<short8*>(Sn) = pa0;
            *reinterpret_cast<short8*>(Sn + 2304) = pa1;
            *reinterpret_cast<short8*>(Sn + 4608) = pb0;
            *reinterpret_cast<short8*>(Sn + 4608 + 2304) = pb1;
        }
        __syncthreads();
    }

    if (MODE == 1) {
        float* C = reinterpret_cast<float*>(z ? o1a : o0a);
        const long crow = bM + wr * 64 + quad * 4;
        const long ccol = (long)blockIdx.x * 128 + wc * 64 + l16;
#pragma unroll
        for (int mt = 0; mt < 4; ++mt)
#pragma unroll
            for (int nt = 0; nt < 4; ++nt)
#pragma unroll
                for (int r = 0; r < 4; ++r)
                    C[(crow + mt * 16 + r) * (long)N + ccol + nt * 16] = acc[mt][nt][r];
        return;
    }

    // MODE 0 epilogue
    if (blockIdx.x < 16) {
        // q (x<8) / k (8..15), packed [bh][t][d]
        short* dst = reinterpret_cast<short*>(blockIdx.x >= 8 ? (z ? o1b : o0b)
                                                              : (z ? o1a : o0a));
        const int hd0 = (int)(blockIdx.x & 7) * 128 + wc * 64;
        const int b = (int)(bM >> 10);
        const int t0 = ((int)bM & 1023) + wr * 64 + quad * 4;
#pragma unroll
        for (int nt = 0; nt < 4; ++nt) {
            const int hd = hd0 + nt * 16 + l16;
            const int h = hd >> 6, d = hd & 63;
            short* dp = dst + ((long)(b * 16 + h) * 1024) * 64 + d;
#pragma unroll
            for (int mt = 0; mt < 4; ++mt)
#pragma unroll
                for (int r = 0; r < 4; ++r)
                    dp[(long)(t0 + mt * 16 + r) * 64] = f2bf(acc[mt][nt][r]);
        }
    } else {
        // V: LDS-transpose wave tile -> vT [bh][d][t], coalesced 16B stores
        short* vT = reinterpret_cast<short*>(z ? o1c : o0c);
        const int h = ((int)blockIdx.x - 16) * 2 + wc;
        const int b = (int)(bM >> 10);
        const int tb = ((int)bM & 1023) + wr * 64;
        short* ws = smem + w * 4608;    // 64 d-rows x 72 shorts, wave-private
#pragma unroll
        for (int nt = 0; nt < 4; ++nt)
#pragma unroll
            for (int mt = 0; mt < 4; ++mt) {
                uint2 uu;
                uu.x = pk2(acc[mt][nt][0], acc[mt][nt][1]);
                uu.y = pk2(acc[mt][nt][2], acc[mt][nt][3]);
                *reinterpret_cast<uint2*>(&ws[(nt * 16 + l16) * 72 + mt * 16 + quad * 4]) = uu;
            }
        short* vbase = vT + (long)(b * 16 + h) * 64 * 1024;
#pragma unroll
        for (int p = 0; p < 8; ++p) {
            const int d = p * 8 + (lane >> 3);
            const int ch = (lane & 7) * 8;
            short8 v = *reinterpret_cast<const short8*>(&ws[d * 72 + ch]);
            *reinterpret_cast<short8*>(&vbase[(long)d * 1024 + tb + ch]) = v;
        }
    }
}

// ---------------- flash attention, S^T formulation, conflict-free 68-short rows ----------------
// Q,K packed [bh][t][d]; V^T [bh][d][t]. grid.x = bh (L2 locality), y = qt, z = stream.
__global__ __launch_bounds__(256)
void attn_kernel(const bf16* __restrict__ q0g, const bf16* __restrict__ k0g,
                 const bf16* __restrict__ v0g, bf16* __restrict__ o0g,
                 const bf16* __restrict__ q1g, const bf16* __restrict__ k1g,
                 const bf16* __restrict__ v1g, bf16* __restrict__ o1g) {
    __shared__ short smem[17408];   // 2 bufs x (K 4352 + V 4352)
    const int bh = blockIdx.x;
    const int qt = blockIdx.y;
    const int z = blockIdx.z;
    const int b = bh >> 4, h = bh & 15;
    const int tid = threadIdx.x, lane = tid & 63, w = tid >> 6;
    const int quad = lane >> 4, l16 = lane & 15;

    const short* Qb = reinterpret_cast<const short*>(z ? q1g : q0g) + (long)bh * 1024 * 64;
    const short* Kb = reinterpret_cast<const short*>(z ? k1g : k0g) + (long)bh * 1024 * 64;
    const short* Vb = reinterpret_cast<const short*>(z ? v1g : v0g) + (long)bh * 64 * 1024;
    short* Ob = reinterpret_cast<short*>(z ? o1g : o0g);

    short8 qb[2][2];
#pragma unroll
    for (int qg = 0; qg < 2; ++qg) {
        const short* Qp = Qb + (long)(qt * 128 + qg * 64 + w * 16 + l16) * 64;
        qb[qg][0] = *reinterpret_cast<const short8*>(Qp + quad * 8);
        qb[qg][1] = *reinterpret_cast<const short8*>(Qp + 32 + quad * 8);
    }

    const int r0 = tid >> 3, c8 = (tid & 7) * 8;
    const short* Kp0 = Kb + (long)r0 * 64 + c8;
    const short* Kp1 = Kp0 + 32L * 64;
    const short* Vp0 = Vb + (long)r0 * 1024 + c8;
    const short* Vp1 = Vp0 + 32L * 1024;
    short* Ld = smem + r0 * 68 + c8;

    const int jbase = 8 * (l16 >> 2) + (l16 & 3);

    f32x4 o[2][4] = {};
    float li[2] = {0.f, 0.f};

    {
        short8 a = *reinterpret_cast<const short8*>(Kp0);
        short8 bq = *reinterpret_cast<const short8*>(Kp1);
        short8 c = *reinterpret_cast<const short8*>(Vp0);
        short8 d = *reinterpret_cast<const short8*>(Vp1);
        *reinterpret_cast<short8*>(Ld) = a;
        *reinterpret_cast<short8*>(Ld + 32 * 68) = bq;
        *reinterpret_cast<short8*>(Ld + 4352) = c;
        *reinterpret_cast<short8*>(Ld + 4352 + 32 * 68) = d;
    }
    __syncthreads();

    for (int iter = 0; iter < 16; ++iter) {
        const int cur = iter & 1;
        short8 pk0, pk1, pv0, pv1;
        if (iter < 15) {
            const long joff = (long)(iter + 1) * 64;
            pk0 = *reinterpret_cast<const short8*>(Kp0 + joff * 64);
            pk1 = *reinterpret_cast<const short8*>(Kp1 + joff * 64);
            pv0 = *reinterpret_cast<const short8*>(Vp0 + joff);
            pv1 = *reinterpret_cast<const short8*>(Vp1 + joff);
        }
        const short* Ks = smem + cur * 8704;
        const short* Vs = Ks + 4352;

        f32x4 st[2][4];
        const short* kbp = Ks + jbase * 68 + quad * 8;
#pragma unroll
        for (int g = 0; g < 4; ++g) {
            const int goff = (g >> 1) * 32 + (g & 1) * 4;
            short8 k0 = *reinterpret_cast<const short8*>(kbp + goff * 68);
            short8 k1 = *reinterpret_cast<const short8*>(kbp + goff * 68 + 32);
#pragma unroll
            for (int qg = 0; qg < 2; ++qg) {
                f32x4 zf = {0.f, 0.f, 0.f, 0.f};
                zf = MFMA_BF16(k0, qb[qg][0], zf);
                zf = MFMA_BF16(k1, qb[qg][1], zf);
                st[qg][g] = zf;
            }
        }

        union { unsigned int u[4]; short8 s; } f0[2], f1[2];
#pragma unroll
        for (int qg = 0; qg < 2; ++qg) {
            float p[4][4];
            float rs = 0.f;
#pragma unroll
            for (int g = 0; g < 4; ++g)
#pragma unroll
                for (int r = 0; r < 4; ++r) {
                    float e = exp2f(st[qg][g][r]);
                    p[g][r] = e;
                    rs += e;
                }
            li[qg] += rs;
            f0[qg].u[0] = pk2(p[0][0], p[0][1]); f0[qg].u[1] = pk2(p[0][2], p[0][3]);
            f0[qg].u[2] = pk2(p[1][0], p[1][1]); f0[qg].u[3] = pk2(p[1][2], p[1][3]);
            f1[qg].u[0] = pk2(p[2][0], p[2][1]); f1[qg].u[1] = pk2(p[2][2], p[2][3]);
            f1[qg].u[2] = pk2(p[3][0], p[3][1]); f1[qg].u[3] = pk2(p[3][2], p[3][3]);
        }

#pragma unroll
        for (int dt = 0; dt < 4; ++dt) {
            const short* vbp = Vs + (dt * 16 + l16) * 68 + quad * 8;
            short8 v0 = *reinterpret_cast<const short8*>(vbp);
            short8 v1 = *reinterpret_cast<const short8*>(vbp + 32);
#pragma unroll
            for (int qg = 0; qg < 2; ++qg) {
                o[qg][dt] = MFMA_BF16(v0, f0[qg].s, o[qg][dt]);
                o[qg][dt] = MFMA_BF16(v1, f1[qg].s, o[qg][dt]);
            }
        }

        if (iter < 15) {
            short* Ln = Ld + (cur ^ 1) * 8704;
            *reinterpret_cast<short8*>(Ln) = pk0;
            *reinterpret_cast<short8*>(Ln + 32 * 68) = pk1;
            *reinterpret_cast<short8*>(Ln + 4352) = pv0;
            *reinterpret_cast<short8*>(Ln + 4352 + 32 * 68) = pv1;
        }
        __syncthreads();
    }

#pragma unroll
    for (int qg = 0; qg < 2; ++qg) {
        li[qg] += __shfl_xor(li[qg], 16);
        li[qg] += __shfl_xor(li[qg], 32);
    }

#pragma unroll
    for (int qg = 0; qg < 2; ++qg) {
        short* Os = smem + qg * 5120 + w * 1280;
        const float rl = 1.0f / li[qg];
#pragma unroll
        for (int dt = 0; dt < 4; ++dt) {
            uint2 uu;
            uu.x = pk2(o[qg][dt][0] * rl, o[qg][dt][1] * rl);
            uu.y = pk2(o[qg][dt][2] * rl, o[qg][dt][3] * rl);
            *reinterpret_cast<uint2*>(&Os[l16 * 80 + dt * 16 + quad * 4]) = uu;
        }
#pragma unroll
        for (int p = 0; p < 2; ++p) {
            int row = p * 8 + (lane >> 3);
            int ch = (lane & 7) * 8;
            short8 v = *reinterpret_cast<const short8*>(&Os[row * 80 + ch]);
            *reinterpret_cast<short8*>(&Ob[((long)(b * 1024) + qt * 128 + qg * 64 + w * 16 + row) * 1024 + h * 64 + ch]) = v;
        }
    }
}

extern "C" void kernel_launch(void* const* d_in, const int* in_sizes, int n_in,
                              void* d_out, int out_size, void* d_ws, size_t ws_size,
                              hipStream_t stream) {
    const float* x     = (const float*)d_in[0];
    const float* y     = (const float*)d_in[1];
    const float* Wqkv1 = (const float*)d_in[2];
    const float* Wqkv2 = (const float*)d_in[3];
    const float* Wout1 = (const float*)d_in[4];
    const float* Wout2 = (const float*)d_in[5];

    char* ws = (char*)d_ws;
    bf16* Wqkv1b = (bf16*)(ws + 0);          // 6291456
    bf16* Wqkv2b = (bf16*)(ws + 6291456);    // 6291456
    bf16* Wout1b = (bf16*)(ws + 12582912);   // 2097152
    bf16* Wout2b = (bf16*)(ws + 14680064);   // 2097152
    bf16* xb     = (bf16*)(ws + 16777216);   // 8388608
    bf16* yb     = (bf16*)(ws + 25165824);   // 8388608
    bf16* q1     = (bf16*)(ws + 33554432);   // 8388608  packed [bh][t][d]
    bf16* k1     = (bf16*)(ws + 41943040);   // 8388608
    bf16* v1T    = (bf16*)(ws + 50331648);   // 8388608  [bh][d][t]
    bf16* q2     = (bf16*)(ws + 58720256);   // 8388608
    bf16* k2     = (bf16*)(ws + 67108864);   // 8388608
    bf16* v2T    = (bf16*)(ws + 75497472);   // 8388608 -> 83886080 (80 MB)
    bf16* xo     = xb;                       // xb dead after qkv GEMM
    bf16* yo     = yb;

    // 1. all converts (x, y, Wout plain; Wqkv permuted+scaled)
    cvt_fused<<<dim3(4096, 6), 256, 0, stream>>>(x, y, Wout1, Wout2, Wqkv1, Wqkv2,
                                                 xb, yb, Wout1b, Wout2b, Wqkv1b, Wqkv2b);

    // 2. qkv GEMM (bf16 A, pipelined K-loop, 36-stride LDS) -> q,k packed + vT
    gemm_k<0><<<dim3(24, 32, 2), 256, 0, stream>>>(xb, Wqkv1b, q1, k1, v1T,
                                                   yb, Wqkv2b, q2, k2, v2T, 3072);

    // 3. cross attention: z=0: softmax(q2 k1^T) v1 -> xo ; z=1: softmax(q1 k2^T) v2 -> yo
    attn_kernel<<<dim3(64, 8, 2), 256, 0, stream>>>(q2, k1, v1T, xo,
                                                    q1, k2, v2T, yo);

    // 4. output projections (fp32 epilogue to d_out)
    gemm_k<1><<<dim3(8, 32, 2), 256, 0, stream>>>(xo, Wout1b, (float*)d_out, nullptr, nullptr,
                                                  yo, Wout2b, ((float*)d_out) + 4194304, nullptr, nullptr,
                                                  1024);
}

// Round 7
// 279.717 us; speedup vs baseline: 2.1246x; 2.1246x over previous
//
#include <hip/hip_runtime.h>
#include <hip/hip_bf16.h>

typedef __hip_bfloat16 bf16;
typedef __attribute__((ext_vector_type(8))) short short8;
typedef __attribute__((ext_vector_type(4))) short short4v;
typedef __attribute__((ext_vector_type(4))) float f32x4;

#define MFMA_BF16(a, b, c) __builtin_amdgcn_mfma_f32_16x16x32_bf16((a), (b), (c), 0, 0, 0)

// 1/sqrt(E/H) * log2(e) folded into Wqkv q-rows: softmax exps become plain exp2
#define QSCALE 0.1803368860111270f

__device__ __forceinline__ short f2bf(float f) {
    union { bf16 h; short s; } u;
    u.h = __float2bfloat16(f);
    return u.s;
}

#if defined(__has_builtin) && __has_builtin(__builtin_amdgcn_cvt_pk_bf16_f32)
typedef __attribute__((ext_vector_type(2))) __bf16 bf16x2_t;
__device__ __forceinline__ unsigned int pk2(float a, float b) {
    union { bf16x2_t v; unsigned int u; } x;
    x.v = __builtin_amdgcn_cvt_pk_bf16_f32(a, b);
    return x.u;
}
#else
__device__ __forceinline__ unsigned int pk2(float a, float b) {
    union { bf16 h[2]; unsigned int u; } x;
    x.h[0] = __float2bfloat16(a);
    x.h[1] = __float2bfloat16(b);
    return x.u;
}
#endif

// ---------------- ALL converts in one dispatch (grid.y selects tensor / mode) ----------------
// R5 lesson: do NOT fold x/y convert into GEMM staging (cvt chain on prefetch -> vmcnt(0) stall).
__global__ void cvt_fused(const float* __restrict__ x, const float* __restrict__ y,
                          const float* __restrict__ wo1, const float* __restrict__ wo2,
                          const float* __restrict__ wq1, const float* __restrict__ wq2,
                          bf16* __restrict__ ox, bf16* __restrict__ oy,
                          bf16* __restrict__ oo1, bf16* __restrict__ oo2,
                          bf16* __restrict__ oq1, bf16* __restrict__ oq2) {
    const int yb = blockIdx.y;
    if (yb < 4) {
        int i = blockIdx.x * 256 + threadIdx.x;
        const float* src; bf16* dst; int n4;
        switch (yb) {
            case 0:  src = x;   dst = ox;  n4 = 1048576; break;
            case 1:  src = y;   dst = oy;  n4 = 1048576; break;
            case 2:  src = wo1; dst = oo1; n4 = 262144;  break;
            default: src = wo2; dst = oo2; n4 = 262144;  break;
        }
        if (i >= n4) return;
        float4 f = reinterpret_cast<const float4*>(src)[i];
        short4v s;
        s.x = f2bf(f.x); s.y = f2bf(f.y); s.z = f2bf(f.z); s.w = f2bf(f.w);
        reinterpret_cast<short4v*>(dst)[i] = s;
    } else {
        // dest row n' = comp*1024 + h*64 + d  <-  src row d*48 + comp*16 + h
        const int np = blockIdx.x;
        if (np >= 3072) return;
        const int comp = np >> 10, rem = np & 1023, h = rem >> 6, d = rem & 63;
        const int srow = d * 48 + comp * 16 + h;
        const float* src = ((yb == 5) ? wq2 : wq1) + (long)srow * 1024;
        bf16* dst = ((yb == 5) ? oq2 : oq1) + (long)np * 1024;
        const float sc = (comp == 0) ? QSCALE : 1.0f;
        int t = threadIdx.x;
        float4 f = reinterpret_cast<const float4*>(src)[t];
        short4v s;
        s.x = f2bf(f.x * sc); s.y = f2bf(f.y * sc); s.z = f2bf(f.z * sc); s.w = f2bf(f.w * sc);
        reinterpret_cast<short4v*>(dst)[t] = s;
    }
}

// ---------------- GEMM, reg-prefetch + LDS dbuf, m97-aligned LDS (32-short rows) ----------------
// R6 lesson: LDS row stride MUST be a multiple of 8 shorts (16B) or short8 DS ops are
// misaligned and serialize (77us -> 267us). Unpadded 32-short rows = m97 known-good.
// MODE 0 (qkv): N=3072. Blocks x<16 (q,k) accumulate C^T via SWAPPED MFMA operands so the
//   4 acc regs run along d -> packed 8B stores to [bh][t][d]. Blocks 16..23: V via LDS
//   transpose -> vT [bh][d][t] coalesced. MODE 1 (out-proj): fp32 C, normal orientation.
template <int MODE>
__global__ __launch_bounds__(256)
void gemm_k(const bf16* __restrict__ A0g, const bf16* __restrict__ B0g,
            void* o0a, void* o0b, void* o0c,
            const bf16* __restrict__ A1g, const bf16* __restrict__ B1g,
            void* o1a, void* o1b, void* o1c, int N) {
    __shared__ short smem[18432];   // 2 bufs x (A 4096 + B 4096); V-epilogue uses 4x4608
    const int z = blockIdx.z;
    const int tid  = threadIdx.x;
    const int lane = tid & 63;
    const int w    = tid >> 6;
    const int wr   = w >> 1;
    const int wc   = w & 1;
    const int quad = lane >> 4;
    const int l16  = lane & 15;
    const long bM = (long)blockIdx.y * 128;
    const bool sw = (MODE == 0) && (blockIdx.x < 16);

    f32x4 acc[4][4] = {};

    const int srow = tid >> 2;          // 0..63
    const int sch  = (tid & 3) * 8;     // k-chunk of 8 bf16
    const short* Ag0 = reinterpret_cast<const short*>(z ? A1g : A0g) + (bM + srow) * 1024 + sch;
    const short* Bg0 = reinterpret_cast<const short*>(z ? B1g : B0g)
                       + ((long)blockIdx.x * 128 + srow) * 1024 + sch;
    const int sbase = tid * 8;          // == srow*32 + sch (m97 layout, 16B aligned)

    // prologue: tile 0 -> buf 0
    {
        short8 a0 = *reinterpret_cast<const short8*>(Ag0);
        short8 a1 = *reinterpret_cast<const short8*>(Ag0 + 65536);
        short8 b0 = *reinterpret_cast<const short8*>(Bg0);
        short8 b1 = *reinterpret_cast<const short8*>(Bg0 + 65536);
        *reinterpret_cast<short8*>(&smem[sbase]) = a0;
        *reinterpret_cast<short8*>(&smem[sbase + 2048]) = a1;
        *reinterpret_cast<short8*>(&smem[sbase + 4096]) = b0;
        *reinterpret_cast<short8*>(&smem[sbase + 4096 + 2048]) = b1;
    }
    __syncthreads();

    for (int iter = 0; iter < 32; ++iter) {
        const int cur = iter & 1;
        short8 pa0, pa1, pb0, pb1;
        if (iter < 31) {
            const int off = (iter + 1) * 32;
            pa0 = *reinterpret_cast<const short8*>(Ag0 + off);
            pa1 = *reinterpret_cast<const short8*>(Ag0 + 65536 + off);
            pb0 = *reinterpret_cast<const short8*>(Bg0 + off);
            pb1 = *reinterpret_cast<const short8*>(Bg0 + 65536 + off);
        }
        const short* Ab = smem + cur * 8192;
        const short* Bb = Ab + 4096;

        short8 af[4], bfr[4];
#pragma unroll
        for (int mt = 0; mt < 4; ++mt)
            af[mt] = *reinterpret_cast<const short8*>(&Ab[(wr * 64 + mt * 16 + l16) * 32 + quad * 8]);
#pragma unroll
        for (int nt = 0; nt < 4; ++nt)
            bfr[nt] = *reinterpret_cast<const short8*>(&Bb[(wc * 64 + nt * 16 + l16) * 32 + quad * 8]);
        if (sw) {
            // C^T: acc[nt][mt], D[hd][t] (lane = t, regs = d)
#pragma unroll
            for (int nt = 0; nt < 4; ++nt)
#pragma unroll
                for (int mt = 0; mt < 4; ++mt)
                    acc[nt][mt] = MFMA_BF16(bfr[nt], af[mt], acc[nt][mt]);
        } else {
#pragma unroll
            for (int mt = 0; mt < 4; ++mt)
#pragma unroll
                for (int nt = 0; nt < 4; ++nt)
                    acc[mt][nt] = MFMA_BF16(af[mt], bfr[nt], acc[mt][nt]);
        }

        if (iter < 31) {
            short* Sn = smem + (cur ^ 1) * 8192 + sbase;
            *reinterpret_cast<short8*>(Sn) = pa0;
            *reinterpret_cast<short8*>(Sn + 2048) = pa1;
            *reinterpret_cast<short8*>(Sn + 4096) = pb0;
            *reinterpret_cast<short8*>(Sn + 4096 + 2048) = pb1;
        }
        __syncthreads();
    }

    if (MODE == 1) {
        float* C = reinterpret_cast<float*>(z ? o1a : o0a);
        const long crow = bM + wr * 64 + quad * 4;
        const long ccol = (long)blockIdx.x * 128 + wc * 64 + l16;
#pragma unroll
        for (int mt = 0; mt < 4; ++mt)
#pragma unroll
            for (int nt = 0; nt < 4; ++nt)
#pragma unroll
                for (int r = 0; r < 4; ++r)
                    C[(crow + mt * 16 + r) * (long)N + ccol + nt * 16] = acc[mt][nt][r];
        return;
    }

    if (sw) {
        // q (x<8) / k (8..15): D[hd][t] -> packed 8B stores to [bh][t][d]
        short* dst = reinterpret_cast<short*>(blockIdx.x >= 8 ? (z ? o1b : o0b)
                                                              : (z ? o1a : o0a));
        const int b = (int)(bM >> 10);
        const int h = (int)(blockIdx.x & 7) * 2 + wc;
        const int tloc = ((int)bM & 1023) + wr * 64 + l16;
        short* dp = dst + (long)(b * 16 + h) * 65536;
#pragma unroll
        for (int nt = 0; nt < 4; ++nt) {
            const int d0 = nt * 16 + quad * 4;
#pragma unroll
            for (int mt = 0; mt < 4; ++mt) {
                const int t = tloc + mt * 16;
                uint2 uu;
                uu.x = pk2(acc[nt][mt][0], acc[nt][mt][1]);
                uu.y = pk2(acc[nt][mt][2], acc[nt][mt][3]);
                *reinterpret_cast<uint2*>(dp + (long)t * 64 + d0) = uu;
            }
        }
    } else {
        // V: LDS-transpose wave tile -> vT [bh][d][t], coalesced 16B stores
        short* vT = reinterpret_cast<short*>(z ? o1c : o0c);
        const int h = ((int)blockIdx.x - 16) * 2 + wc;
        const int b = (int)(bM >> 10);
        const int tb = ((int)bM & 1023) + wr * 64;
        short* ws = smem + w * 4608;    // 64 d-rows x 72 shorts, wave-private
#pragma unroll
        for (int nt = 0; nt < 4; ++nt)
#pragma unroll
            for (int mt = 0; mt < 4; ++mt) {
                uint2 uu;
                uu.x = pk2(acc[mt][nt][0], acc[mt][nt][1]);
                uu.y = pk2(acc[mt][nt][2], acc[mt][nt][3]);
                *reinterpret_cast<uint2*>(&ws[(nt * 16 + l16) * 72 + mt * 16 + quad * 4]) = uu;
            }
        short* vbase = vT + (long)(b * 16 + h) * 64 * 1024;
#pragma unroll
        for (int p = 0; p < 8; ++p) {
            const int d = p * 8 + (lane >> 3);
            const int ch = (lane & 7) * 8;
            short8 v = *reinterpret_cast<const short8*>(&ws[d * 72 + ch]);
            *reinterpret_cast<short8*>(&vbase[(long)d * 1024 + tb + ch]) = v;
        }
    }
}

// ---------------- flash attention, S^T formulation (R4-verified, 80-short aligned rows) ----------------
// Q,K packed [bh][t][d]; V^T [bh][d][t]. grid.x = bh (L2 locality), y = qt, z = stream.
__global__ __launch_bounds__(256)
void attn_kernel(const bf16* __restrict__ q0g, const bf16* __restrict__ k0g,
                 const bf16* __restrict__ v0g, bf16* __restrict__ o0g,
                 const bf16* __restrict__ q1g, const bf16* __restrict__ k1g,
                 const bf16* __restrict__ v1g, bf16* __restrict__ o1g) {
    __shared__ short smem[20480];
    const int bh = blockIdx.x;
    const int qt = blockIdx.y;
    const int z = blockIdx.z;
    const int b = bh >> 4, h = bh & 15;
    const int tid = threadIdx.x, lane = tid & 63, w = tid >> 6;
    const int quad = lane >> 4, l16 = lane & 15;

    const short* Qb = reinterpret_cast<const short*>(z ? q1g : q0g) + (long)bh * 1024 * 64;
    const short* Kb = reinterpret_cast<const short*>(z ? k1g : k0g) + (long)bh * 1024 * 64;
    const short* Vb = reinterpret_cast<const short*>(z ? v1g : v0g) + (long)bh * 64 * 1024;
    short* Ob = reinterpret_cast<short*>(z ? o1g : o0g);

    short8 qb[2][2];
#pragma unroll
    for (int qg = 0; qg < 2; ++qg) {
        const short* Qp = Qb + (long)(qt * 128 + qg * 64 + w * 16 + l16) * 64;
        qb[qg][0] = *reinterpret_cast<const short8*>(Qp + quad * 8);
        qb[qg][1] = *reinterpret_cast<const short8*>(Qp + 32 + quad * 8);
    }

    const int r0 = tid >> 3, c8 = (tid & 7) * 8;
    const short* Kp0 = Kb + (long)r0 * 64 + c8;
    const short* Kp1 = Kp0 + 32L * 64;
    const short* Vp0 = Vb + (long)r0 * 1024 + c8;
    const short* Vp1 = Vp0 + 32L * 1024;
    short* Ld = smem + r0 * 80 + c8;

    const int jbase = 8 * (l16 >> 2) + (l16 & 3);

    f32x4 o[2][4] = {};
    float li[2] = {0.f, 0.f};

    {
        short8 a = *reinterpret_cast<const short8*>(Kp0);
        short8 bq = *reinterpret_cast<const short8*>(Kp1);
        short8 c = *reinterpret_cast<const short8*>(Vp0);
        short8 d = *reinterpret_cast<const short8*>(Vp1);
        *reinterpret_cast<short8*>(Ld) = a;
        *reinterpret_cast<short8*>(Ld + 32 * 80) = bq;
        *reinterpret_cast<short8*>(Ld + 5120) = c;
        *reinterpret_cast<short8*>(Ld + 5120 + 32 * 80) = d;
    }
    __syncthreads();

    for (int iter = 0; iter < 16; ++iter) {
        const int cur = iter & 1;
        short8 pk0, pk1, pv0, pv1;
        if (iter < 15) {
            const long joff = (long)(iter + 1) * 64;
            pk0 = *reinterpret_cast<const short8*>(Kp0 + joff * 64);
            pk1 = *reinterpret_cast<const short8*>(Kp1 + joff * 64);
            pv0 = *reinterpret_cast<const short8*>(Vp0 + joff);
            pv1 = *reinterpret_cast<const short8*>(Vp1 + joff);
        }
        const short* Ks = smem + cur * 10240;
        const short* Vs = Ks + 5120;

        f32x4 st[2][4];
        const short* kbp = Ks + jbase * 80 + quad * 8;
#pragma unroll
        for (int g = 0; g < 4; ++g) {
            const int goff = (g >> 1) * 32 + (g & 1) * 4;
            short8 k0 = *reinterpret_cast<const short8*>(kbp + goff * 80);
            short8 k1 = *reinterpret_cast<const short8*>(kbp + goff * 80 + 32);
#pragma unroll
            for (int qg = 0; qg < 2; ++qg) {
                f32x4 zf = {0.f, 0.f, 0.f, 0.f};
                zf = MFMA_BF16(k0, qb[qg][0], zf);
                zf = MFMA_BF16(k1, qb[qg][1], zf);
                st[qg][g] = zf;
            }
        }

        union { unsigned int u[4]; short8 s; } f0[2], f1[2];
#pragma unroll
        for (int qg = 0; qg < 2; ++qg) {
            float p[4][4];
            float rs = 0.f;
#pragma unroll
            for (int g = 0; g < 4; ++g)
#pragma unroll
                for (int r = 0; r < 4; ++r) {
                    float e = exp2f(st[qg][g][r]);
                    p[g][r] = e;
                    rs += e;
                }
            li[qg] += rs;
            f0[qg].u[0] = pk2(p[0][0], p[0][1]); f0[qg].u[1] = pk2(p[0][2], p[0][3]);
            f0[qg].u[2] = pk2(p[1][0], p[1][1]); f0[qg].u[3] = pk2(p[1][2], p[1][3]);
            f1[qg].u[0] = pk2(p[2][0], p[2][1]); f1[qg].u[1] = pk2(p[2][2], p[2][3]);
            f1[qg].u[2] = pk2(p[3][0], p[3][1]); f1[qg].u[3] = pk2(p[3][2], p[3][3]);
        }

#pragma unroll
        for (int dt = 0; dt < 4; ++dt) {
            const short* vbp = Vs + (dt * 16 + l16) * 80 + quad * 8;
            short8 v0 = *reinterpret_cast<const short8*>(vbp);
            short8 v1 = *reinterpret_cast<const short8*>(vbp + 32);
#pragma unroll
            for (int qg = 0; qg < 2; ++qg) {
                o[qg][dt] = MFMA_BF16(v0, f0[qg].s, o[qg][dt]);
                o[qg][dt] = MFMA_BF16(v1, f1[qg].s, o[qg][dt]);
            }
        }

        if (iter < 15) {
            short* Ln = Ld + (cur ^ 1) * 10240;
            *reinterpret_cast<short8*>(Ln) = pk0;
            *reinterpret_cast<short8*>(Ln + 32 * 80) = pk1;
            *reinterpret_cast<short8*>(Ln + 5120) = pv0;
            *reinterpret_cast<short8*>(Ln + 5120 + 32 * 80) = pv1;
        }
        __syncthreads();
    }

#pragma unroll
    for (int qg = 0; qg < 2; ++qg) {
        li[qg] += __shfl_xor(li[qg], 16);
        li[qg] += __shfl_xor(li[qg], 32);
    }

#pragma unroll
    for (int qg = 0; qg < 2; ++qg) {
        short* Os = smem + qg * 5120 + w * 1280;
        const float rl = 1.0f / li[qg];
#pragma unroll
        for (int dt = 0; dt < 4; ++dt) {
            uint2 uu;
            uu.x = pk2(o[qg][dt][0] * rl, o[qg][dt][1] * rl);
            uu.y = pk2(o[qg][dt][2] * rl, o[qg][dt][3] * rl);
            *reinterpret_cast<uint2*>(&Os[l16 * 80 + dt * 16 + quad * 4]) = uu;
        }
#pragma unroll
        for (int p = 0; p < 2; ++p) {
            int row = p * 8 + (lane >> 3);
            int ch = (lane & 7) * 8;
            short8 v = *reinterpret_cast<const short8*>(&Os[row * 80 + ch]);
            *reinterpret_cast<short8*>(&Ob[((long)(b * 1024) + qt * 128 + qg * 64 + w * 16 + row) * 1024 + h * 64 + ch]) = v;
        }
    }
}

extern "C" void kernel_launch(void* const* d_in, const int* in_sizes, int n_in,
                              void* d_out, int out_size, void* d_ws, size_t ws_size,
                              hipStream_t stream) {
    const float* x     = (const float*)d_in[0];
    const float* y     = (const float*)d_in[1];
    const float* Wqkv1 = (const float*)d_in[2];
    const float* Wqkv2 = (const float*)d_in[3];
    const float* Wout1 = (const float*)d_in[4];
    const float* Wout2 = (const float*)d_in[5];

    char* ws = (char*)d_ws;
    bf16* Wqkv1b = (bf16*)(ws + 0);          // 6291456
    bf16* Wqkv2b = (bf16*)(ws + 6291456);    // 6291456
    bf16* Wout1b = (bf16*)(ws + 12582912);   // 2097152
    bf16* Wout2b = (bf16*)(ws + 14680064);   // 2097152
    bf16* xb     = (bf16*)(ws + 16777216);   // 8388608
    bf16* yb     = (bf16*)(ws + 25165824);   // 8388608
    bf16* q1     = (bf16*)(ws + 33554432);   // 8388608  packed [bh][t][d]
    bf16* k1     = (bf16*)(ws + 41943040);   // 8388608
    bf16* v1T    = (bf16*)(ws + 50331648);   // 8388608  [bh][d][t]
    bf16* q2     = (bf16*)(ws + 58720256);   // 8388608
    bf16* k2     = (bf16*)(ws + 67108864);   // 8388608
    bf16* v2T    = (bf16*)(ws + 75497472);   // 8388608 -> 83886080 (80 MB)
    bf16* xo     = xb;                       // xb dead after qkv GEMM
    bf16* yo     = yb;

    // 1. all converts (x, y, Wout plain; Wqkv permuted+scaled)
    cvt_fused<<<dim3(4096, 6), 256, 0, stream>>>(x, y, Wout1, Wout2, Wqkv1, Wqkv2,
                                                 xb, yb, Wout1b, Wout2b, Wqkv1b, Wqkv2b);

    // 2. qkv GEMM (m97-aligned LDS, reg-prefetch dbuf) -> q,k packed (C^T stores) + vT
    gemm_k<0><<<dim3(24, 32, 2), 256, 0, stream>>>(xb, Wqkv1b, q1, k1, v1T,
                                                   yb, Wqkv2b, q2, k2, v2T, 3072);

    // 3. cross attention: z=0: softmax(q2 k1^T) v1 -> xo ; z=1: softmax(q1 k2^T) v2 -> yo
    attn_kernel<<<dim3(64, 8, 2), 256, 0, stream>>>(q2, k1, v1T, xo,
                                                    q1, k2, v2T, yo);

    // 4. output projections (fp32 epilogue to d_out)
    gemm_k<1><<<dim3(8, 32, 2), 256, 0, stream>>>(xo, Wout1b, (float*)d_out, nullptr, nullptr,
                                                  yo, Wout2b, ((float*)d_out) + 4194304, nullptr, nullptr,
                                                  1024);
}